// Round 3
// baseline (288.795 us; speedup 1.0000x reference)
//
#include <hip/hip_runtime.h>
#include <math.h>

typedef unsigned short u16;
typedef __attribute__((ext_vector_type(8))) short short8;
typedef __attribute__((ext_vector_type(4))) float f32x4;
typedef __attribute__((ext_vector_type(4))) unsigned short u16x4;
typedef __attribute__((ext_vector_type(8))) unsigned short u16x8;

#define N_TOK 2048
#define DIM 1024
#define OUT_ELEMS 2097152   // N_TOK * DIM

#define GLDS16(gp, lp) __builtin_amdgcn_global_load_lds( \
    (const __attribute__((address_space(1))) unsigned int*)(gp), \
    (__attribute__((address_space(3))) unsigned int*)(lp), 16, 0, 0)

__device__ __forceinline__ u16 f2bf(float f) {
    union { float f; unsigned u; } v; v.f = f;
    unsigned r = (v.u + 0x7FFFu + ((v.u >> 16) & 1u)) >> 16;
    return (u16)r;
}
__device__ __forceinline__ float bf2f(u16 h) {
    union { unsigned u; float f; } v; v.u = ((unsigned)h) << 16;
    return v.f;
}

// ------- init: shared-expert token list, cursors, Psum/cnt zeros ----------
__global__ void k_init(int* __restrict__ tlist, int* __restrict__ curs,
                       float* __restrict__ Psum, int* __restrict__ cnt8) {
    int i = blockIdx.x * 256 + threadIdx.x;   // 0..2047
    tlist[4096 + i] = i;
    if (i < 16) curs[i] = 0;
    if (i < 8) { Psum[i] = 0.f; cnt8[i] = 0; }
}

// ---------------- x fp32 -> bf16 ----------------
__global__ void k_cvt_x(const float* __restrict__ x, u16* __restrict__ xb) {
    int i = blockIdx.x * 256 + threadIdx.x;     // one thread = 4 elems
    f32x4 v = ((const f32x4*)x)[i];
    u16x4 o;
    o.x = f2bf(v.x); o.y = f2bf(v.y); o.z = f2bf(v.z); o.w = f2bf(v.w);
    ((u16x4*)xb)[i] = o;
}

// ------- weights: fp32 [K,N] -> bf16 transposed [N,K], 64x64 tiles --------
// read f32x4/lane (coalesced 1KB/wave), LDS [64][68] (2-way banks = free),
// write u16x8/lane.
__global__ void k_cvt_w(const float* __restrict__ wg, const float* __restrict__ wu,
                        const float* __restrict__ wd, const float* __restrict__ wsg,
                        const float* __restrict__ wsu, const float* __restrict__ wsd,
                        u16* __restrict__ wgt, u16* __restrict__ wut,
                        u16* __restrict__ wdt, u16* __restrict__ wsgt,
                        u16* __restrict__ wsut, u16* __restrict__ wsdt) {
    __shared__ float tile[64 * 68];
    int bx = blockIdx.x;
    int mat = bx >> 8;
    int tl  = bx & 255;
    int tr = tl >> 4, tc = tl & 15;
    const float* src; u16* dst;
    if      (mat <  8) { src = wg  + (size_t)mat * 1048576;        dst = wgt + (size_t)mat * 1048576; }
    else if (mat < 16) { src = wu  + (size_t)(mat - 8) * 1048576;  dst = wut + (size_t)(mat - 8) * 1048576; }
    else if (mat < 24) { src = wd  + (size_t)(mat - 16) * 1048576; dst = wdt + (size_t)(mat - 16) * 1048576; }
    else if (mat == 24){ src = wsg; dst = wsgt; }
    else if (mat == 25){ src = wsu; dst = wsut; }
    else               { src = wsd; dst = wsdt; }
    int t = threadIdx.x;
    int col = (t & 15) * 4;       // 0..60
    int rbase = t >> 4;           // 0..15
#pragma unroll
    for (int j = 0; j < 4; j++) {
        int row = rbase + j * 16;
        f32x4 v = *(const f32x4*)(src + (size_t)(tr * 64 + row) * 1024 + tc * 64 + col);
        *(f32x4*)(tile + row * 68 + col) = v;
    }
    __syncthreads();
    int oc = t & 63;              // output row (orig col)
    int q  = t >> 6;              // 0..3
#pragma unroll
    for (int j = 0; j < 2; j++) {
        int kb = q * 8 + j * 32;  // orig row base (output k base)
        u16x8 o;
#pragma unroll
        for (int i = 0; i < 8; i++) o[i] = f2bf(tile[(kb + i) * 68 + oc]);
        *(u16x8*)(dst + (size_t)(tc * 64 + oc) * 1024 + tr * 64 + kb) = o;
    }
}

// -------- router: logits, top-2 weights, block-partial Psum/counts --------
__global__ void k_router(const float* __restrict__ x, const float* __restrict__ wgate,
                         int* __restrict__ tidx, float* __restrict__ tw,
                         float* __restrict__ Psum, int* __restrict__ cnt8) {
    __shared__ float sP[8];
    __shared__ int   sC[8];
    int t = threadIdx.x;
    if (t < 8) { sP[t] = 0.f; sC[t] = 0; }
    __syncthreads();
    int wave = t >> 6;
    int lane = t & 63;
    int n = blockIdx.x * 4 + wave;
    const float* xr = x + (size_t)n * DIM;
    float acc[8] = {0.f,0.f,0.f,0.f,0.f,0.f,0.f,0.f};
    for (int d = lane; d < DIM; d += 64) {
        float xv = xr[d];
        const float* wr = wgate + d * 8;
#pragma unroll
        for (int e = 0; e < 8; e++) acc[e] += xv * wr[e];
    }
#pragma unroll
    for (int off = 32; off; off >>= 1) {
#pragma unroll
        for (int e = 0; e < 8; e++) acc[e] += __shfl_xor(acc[e], off);
    }
    if (lane == 0) {
        float mx = acc[0];
#pragma unroll
        for (int e = 1; e < 8; e++) mx = fmaxf(mx, acc[e]);
        float p[8], s = 0.f;
#pragma unroll
        for (int e = 0; e < 8; e++) { p[e] = expf(acc[e] - mx); s += p[e]; }
        float inv = 1.f / s;
#pragma unroll
        for (int e = 0; e < 8; e++) atomicAdd(&sP[e], p[e] * inv);
        int i0 = 0; float b0 = acc[0];
#pragma unroll
        for (int e = 1; e < 8; e++) if (acc[e] > b0) { b0 = acc[e]; i0 = e; }
        int i1 = -1; float b1 = -3.4e38f;
#pragma unroll
        for (int e = 0; e < 8; e++) if (e != i0 && acc[e] > b1) { b1 = acc[e]; i1 = e; }
        float w0 = 1.f / (1.f + expf(b1 - b0));
        tidx[n * 2] = i0; tidx[n * 2 + 1] = i1;
        tw[n * 2] = w0;   tw[n * 2 + 1] = 1.f - w0;
        atomicAdd(&sC[i0], 1);
        atomicAdd(&sC[i1], 1);
    }
    __syncthreads();
    if (t < 8) {
        atomicAdd(&Psum[t], sP[t]);
        atomicAdd(&cnt8[t], sC[t]);
    }
}

// -------- finalize: aux loss, counts, offsets ----------
__global__ void k_finalize(const float* __restrict__ Psum, const int* __restrict__ cnt8,
                           float* __restrict__ out, int* __restrict__ counts,
                           int* __restrict__ offs) {
    if (threadIdx.x == 0) {
        float aux = 0.f;
        int o = 0;
        for (int e = 0; e < 8; e++) {
            int c = cnt8[e];
            aux += (float)c * Psum[e];
            offs[e] = o; counts[e] = c; o += c;
        }
        out[OUT_ELEMS] = 8.f * aux / ((float)N_TOK * (float)N_TOK);
        offs[8] = 4096; counts[8] = 2048;
    }
}

// ---------------- scatter tokens into expert lists, record slots ------------
__global__ void k_scatter(const int* __restrict__ tidx, const int* __restrict__ offs,
                          int* __restrict__ curs, int* __restrict__ tlist,
                          int* __restrict__ slots) {
    int n = blockIdx.x * 256 + threadIdx.x;
    if (n >= N_TOK) return;
#pragma unroll
    for (int k = 0; k < 2; k++) {
        int e = tidx[n * 2 + k];
        int p = atomicAdd(&curs[e], 1);
        int sl = offs[e] + p;
        tlist[sl] = n;
        slots[n * 2 + k] = sl;
    }
}

// ---------------- GEMM1: gathered X @ [Wg|Wu], fused silu*u -> H bf16 -------
__global__ __launch_bounds__(256, 2)
void k_gemm1(const u16* __restrict__ xb, const u16* __restrict__ wgt,
             const u16* __restrict__ wut, const u16* __restrict__ wsgt,
             const u16* __restrict__ wsut, const int* __restrict__ tlist,
             const int* __restrict__ counts, const int* __restrict__ offs,
             u16* __restrict__ H) {
    int bx = blockIdx.x;
    int job = bx >> 7;
    int mt = (bx >> 3) & 15;
    int nt = bx & 7;
    int jcnt = counts[job];
    int m0 = mt << 7;
    if (m0 >= jcnt) return;
    int joff = offs[job];
    int n0 = nt << 7;
    const u16* Bg = (job < 8) ? (wgt + (size_t)job * 1048576) : wsgt;
    const u16* Bu = (job < 8) ? (wut + (size_t)job * 1048576) : wsut;

    __shared__ __attribute__((aligned(128))) u16 As[4096];
    __shared__ __attribute__((aligned(128))) u16 Bgs[4096];
    __shared__ __attribute__((aligned(128))) u16 Bus[4096];

    int t = threadIdx.x;
    int wave = t >> 6, lane = t & 63;
    int ch = (lane & 3) * 8;
    int r0 = (wave * 2 + 0) * 16 + (lane >> 2);
    int r1 = (wave * 2 + 1) * 16 + (lane >> 2);
    int tok0 = tlist[joff + m0 + r0];
    int tok1 = tlist[joff + m0 + r1];
    const u16* a0 = xb + (size_t)tok0 * 1024 + ch;
    const u16* a1 = xb + (size_t)tok1 * 1024 + ch;
    const u16* g0 = Bg + (size_t)(n0 + r0) * 1024 + ch;
    const u16* g1 = Bg + (size_t)(n0 + r1) * 1024 + ch;
    const u16* u0 = Bu + (size_t)(n0 + r0) * 1024 + ch;
    const u16* u1 = Bu + (size_t)(n0 + r1) * 1024 + ch;
    u16* lA0 = As  + (wave * 2 + 0) * 512;  u16* lA1 = As  + (wave * 2 + 1) * 512;
    u16* lG0 = Bgs + (wave * 2 + 0) * 512;  u16* lG1 = Bgs + (wave * 2 + 1) * 512;
    u16* lU0 = Bus + (wave * 2 + 0) * 512;  u16* lU1 = Bus + (wave * 2 + 1) * 512;

    int wm = (wave >> 1) << 6, wn = (wave & 1) << 6;
    int quad = lane >> 4, lr = lane & 15;

    f32x4 accg[4][4], accu[4][4];
    f32x4 zz = {0.f, 0.f, 0.f, 0.f};
#pragma unroll
    for (int i = 0; i < 4; i++)
#pragma unroll
        for (int j = 0; j < 4; j++) { accg[i][j] = zz; accu[i][j] = zz; }

    for (int k0 = 0; k0 < 1024; k0 += 32) {
        GLDS16(a0 + k0, lA0);  GLDS16(a1 + k0, lA1);
        GLDS16(g0 + k0, lG0);  GLDS16(g1 + k0, lG1);
        GLDS16(u0 + k0, lU0);  GLDS16(u1 + k0, lU1);
        __syncthreads();
        short8 af[4], bgf[4], buf[4];
#pragma unroll
        for (int i = 0; i < 4; i++) {
            af[i]  = *(const short8*)(As  + (wm + i * 16 + lr) * 32 + quad * 8);
            bgf[i] = *(const short8*)(Bgs + (wn + i * 16 + lr) * 32 + quad * 8);
            buf[i] = *(const short8*)(Bus + (wn + i * 16 + lr) * 32 + quad * 8);
        }
#pragma unroll
        for (int mi = 0; mi < 4; mi++)
#pragma unroll
            for (int ni = 0; ni < 4; ni++) {
                accg[mi][ni] = __builtin_amdgcn_mfma_f32_16x16x32_bf16(af[mi], bgf[ni], accg[mi][ni], 0, 0, 0);
                accu[mi][ni] = __builtin_amdgcn_mfma_f32_16x16x32_bf16(af[mi], buf[ni], accu[mi][ni], 0, 0, 0);
            }
        __syncthreads();
    }
#pragma unroll
    for (int mi = 0; mi < 4; mi++) {
        int rowb = m0 + wm + mi * 16 + quad * 4;
#pragma unroll
        for (int rr = 0; rr < 4; rr++) {
            int row = rowb + rr;
            if (row < jcnt) {
                size_t base = (size_t)(joff + row) * 1024 + n0 + wn;
#pragma unroll
                for (int ni = 0; ni < 4; ni++) {
                    float g = accg[mi][ni][rr];
                    float u = accu[mi][ni][rr];
                    float h = (g / (1.f + expf(-g))) * u;
                    H[base + ni * 16 + lr] = f2bf(h);
                }
            }
        }
    }
}

// ---------------- GEMM2: H @ Wd -> Y bf16 (unweighted, no atomics) ----------
__global__ __launch_bounds__(256, 2)
void k_gemm2(const u16* __restrict__ H, const u16* __restrict__ wdt,
             const u16* __restrict__ wsdt, const int* __restrict__ counts,
             const int* __restrict__ offs, u16* __restrict__ Y) {
    int bx = blockIdx.x;
    int job = bx >> 7;
    int mt = (bx >> 3) & 15;
    int nt = bx & 7;
    int jcnt = counts[job];
    int m0 = mt << 7;
    if (m0 >= jcnt) return;
    int joff = offs[job];
    int n0 = nt << 7;
    const u16* Bt = (job < 8) ? (wdt + (size_t)job * 1048576) : wsdt;

    __shared__ __attribute__((aligned(128))) u16 As[4096];
    __shared__ __attribute__((aligned(128))) u16 Bs[4096];

    int t = threadIdx.x;
    int wave = t >> 6, lane = t & 63;
    int ch = (lane & 3) * 8;
    int r0 = (wave * 2 + 0) * 16 + (lane >> 2);
    int r1 = (wave * 2 + 1) * 16 + (lane >> 2);
    const u16* a0 = H + (size_t)(joff + m0 + r0) * 1024 + ch;
    const u16* a1 = H + (size_t)(joff + m0 + r1) * 1024 + ch;
    const u16* b0 = Bt + (size_t)(n0 + r0) * 1024 + ch;
    const u16* b1 = Bt + (size_t)(n0 + r1) * 1024 + ch;
    u16* lA0 = As + (wave * 2 + 0) * 512;  u16* lA1 = As + (wave * 2 + 1) * 512;
    u16* lB0 = Bs + (wave * 2 + 0) * 512;  u16* lB1 = Bs + (wave * 2 + 1) * 512;

    int wm = (wave >> 1) << 6, wn = (wave & 1) << 6;
    int quad = lane >> 4, lr = lane & 15;

    f32x4 acc[4][4];
    f32x4 zz = {0.f, 0.f, 0.f, 0.f};
#pragma unroll
    for (int i = 0; i < 4; i++)
#pragma unroll
        for (int j = 0; j < 4; j++) acc[i][j] = zz;

    for (int k0 = 0; k0 < 1024; k0 += 32) {
        GLDS16(a0 + k0, lA0);  GLDS16(a1 + k0, lA1);
        GLDS16(b0 + k0, lB0);  GLDS16(b1 + k0, lB1);
        __syncthreads();
        short8 af[4], bf[4];
#pragma unroll
        for (int i = 0; i < 4; i++) {
            af[i] = *(const short8*)(As + (wm + i * 16 + lr) * 32 + quad * 8);
            bf[i] = *(const short8*)(Bs + (wn + i * 16 + lr) * 32 + quad * 8);
        }
#pragma unroll
        for (int mi = 0; mi < 4; mi++)
#pragma unroll
            for (int ni = 0; ni < 4; ni++)
                acc[mi][ni] = __builtin_amdgcn_mfma_f32_16x16x32_bf16(af[mi], bf[ni], acc[mi][ni], 0, 0, 0);
        __syncthreads();
    }
#pragma unroll
    for (int mi = 0; mi < 4; mi++) {
        int rowb = m0 + wm + mi * 16 + quad * 4;
#pragma unroll
        for (int rr = 0; rr < 4; rr++) {
            int row = rowb + rr;
            if (row < jcnt) {
                u16* yrow = Y + (size_t)(joff + row) * 1024 + n0 + wn;
#pragma unroll
                for (int ni = 0; ni < 4; ni++)
                    yrow[ni * 16 + lr] = f2bf(acc[mi][ni][rr]);
            }
        }
    }
}

// ---------------- combine: out[n] = w0*Y[s0] + w1*Y[s1] + Y[4096+n] ---------
__global__ void k_combine(const u16* __restrict__ Y, const int* __restrict__ slots,
                          const float* __restrict__ tw, float* __restrict__ out) {
    int n = blockIdx.x;
    int d = threadIdx.x;
    int s0 = slots[n * 2], s1 = slots[n * 2 + 1];
    float w0 = tw[n * 2], w1 = tw[n * 2 + 1];
    u16x4 y0 = ((const u16x4*)(Y + (size_t)s0 * 1024))[d];
    u16x4 y1 = ((const u16x4*)(Y + (size_t)s1 * 1024))[d];
    u16x4 ys = ((const u16x4*)(Y + (size_t)(4096 + n) * 1024))[d];
    f32x4 r;
    r.x = w0 * bf2f(y0.x) + w1 * bf2f(y1.x) + bf2f(ys.x);
    r.y = w0 * bf2f(y0.y) + w1 * bf2f(y1.y) + bf2f(ys.y);
    r.z = w0 * bf2f(y0.z) + w1 * bf2f(y1.z) + bf2f(ys.z);
    r.w = w0 * bf2f(y0.w) + w1 * bf2f(y1.w) + bf2f(ys.w);
    ((f32x4*)(out + (size_t)n * 1024))[d] = r;
}

extern "C" void kernel_launch(void* const* d_in, const int* in_sizes, int n_in,
                              void* d_out, int out_size, void* d_ws, size_t ws_size,
                              hipStream_t stream) {
    const float* x     = (const float*)d_in[0];
    const float* wgate = (const float*)d_in[1];
    const float* wg    = (const float*)d_in[2];
    const float* wu    = (const float*)d_in[3];
    const float* wd    = (const float*)d_in[4];
    const float* wsg   = (const float*)d_in[5];
    const float* wsu   = (const float*)d_in[6];
    const float* wsd   = (const float*)d_in[7];
    float* out = (float*)d_out;

    char* ws = (char*)d_ws;
    u16*   xb    = (u16*)(ws + 0);           // 4 MB
    u16*   wgt   = (u16*)(ws + 4194304);     // 16 MB
    u16*   wut   = (u16*)(ws + 20971520);    // 16 MB
    u16*   wdt   = (u16*)(ws + 37748736);    // 16 MB
    u16*   wsgt  = (u16*)(ws + 54525952);    // 2 MB
    u16*   wsut  = (u16*)(ws + 56623104);    // 2 MB
    u16*   wsdt  = (u16*)(ws + 58720256);    // 2 MB
    u16*   H     = (u16*)(ws + 60817408);    // 12 MB
    // Y (bf16) overlays wgt (dead after gemm1; gemm2 runs strictly after)
    u16*   Y     = (u16*)(ws + 4194304);     // 6144*1024*2 = 12.58 MB
    int*   tidx  = (int*)(ws + 73400320);
    float* tw    = (float*)(ws + 73416704);
    int*   tlist = (int*)(ws + 73433088);
    int*   slots = (int*)(ws + 73457664);
    int*   counts= (int*)(ws + 73474048);
    int*   offs  = (int*)(ws + 73474112);
    int*   curs  = (int*)(ws + 73474176);
    float* Psum  = (float*)(ws + 73474240);
    int*   cnt8  = (int*)(ws + 73474304);

    k_init<<<8, 256, 0, stream>>>(tlist, curs, Psum, cnt8);
    k_cvt_x<<<2048, 256, 0, stream>>>(x, xb);
    k_router<<<512, 256, 0, stream>>>(x, wgate, tidx, tw, Psum, cnt8);
    k_finalize<<<1, 64, 0, stream>>>(Psum, cnt8, out, counts, offs);
    k_scatter<<<8, 256, 0, stream>>>(tidx, offs, curs, tlist, slots);
    k_cvt_w<<<6912, 256, 0, stream>>>(wg, wu, wd, wsg, wsu, wsd,
                                      wgt, wut, wdt, wsgt, wsut, wsdt);
    k_gemm1<<<1152, 256, 0, stream>>>(xb, wgt, wut, wsgt, wsut, tlist, counts, offs, H);
    k_gemm2<<<1152, 256, 0, stream>>>(H, wdt, wsdt, counts, offs, Y);
    k_combine<<<2048, 256, 0, stream>>>(Y, slots, tw, out);
}

// Round 4
// 280.206 us; speedup vs baseline: 1.0307x; 1.0307x over previous
//
#include <hip/hip_runtime.h>
#include <math.h>

typedef unsigned short u16;
typedef __attribute__((ext_vector_type(8))) short short8;
typedef __attribute__((ext_vector_type(4))) float f32x4;
typedef __attribute__((ext_vector_type(4))) unsigned short u16x4;
typedef __attribute__((ext_vector_type(8))) unsigned short u16x8;

#define N_TOK 2048
#define DIM 1024
#define OUT_ELEMS 2097152   // N_TOK * DIM

#define GLDS16(gp, lp) __builtin_amdgcn_global_load_lds( \
    (const __attribute__((address_space(1))) unsigned int*)(gp), \
    (__attribute__((address_space(3))) unsigned int*)(lp), 16, 0, 0)

__device__ __forceinline__ u16 f2bf(float f) {
    union { float f; unsigned u; } v; v.f = f;
    unsigned r = (v.u + 0x7FFFu + ((v.u >> 16) & 1u)) >> 16;
    return (u16)r;
}
__device__ __forceinline__ float bf2f(u16 h) {
    union { unsigned u; float f; } v; v.u = ((unsigned)h) << 16;
    return v.f;
}

// -------- x fp32 -> bf16, fused init (shared list, cursors, Psum/cnt) ------
__global__ void k_cvt_x(const float* __restrict__ x, u16* __restrict__ xb,
                        int* __restrict__ tlist, int* __restrict__ curs,
                        float* __restrict__ Psum, int* __restrict__ cnt8) {
    int i = blockIdx.x * 256 + threadIdx.x;     // one thread = 4 elems
    f32x4 v = ((const f32x4*)x)[i];
    u16x4 o;
    o.x = f2bf(v.x); o.y = f2bf(v.y); o.z = f2bf(v.z); o.w = f2bf(v.w);
    ((u16x4*)xb)[i] = o;
    if (i < 2048) tlist[4096 + i] = i;
    if (i < 16) curs[i] = 0;
    if (i < 8) { Psum[i] = 0.f; cnt8[i] = 0; }
}

// ------- weights: fp32 [K,N] -> bf16 transposed [N,K], 64x64 tiles --------
// LDS stride 65 (odd): both phases exactly 2-way bank aliasing = free.
// Writes: lanes 0..7 cover 128B contiguous of one output row (8x128B/wave).
__global__ void k_cvt_w(const float* __restrict__ wg, const float* __restrict__ wu,
                        const float* __restrict__ wd, const float* __restrict__ wsg,
                        const float* __restrict__ wsu, const float* __restrict__ wsd,
                        u16* __restrict__ wgt, u16* __restrict__ wut,
                        u16* __restrict__ wdt, u16* __restrict__ wsgt,
                        u16* __restrict__ wsut, u16* __restrict__ wsdt) {
    __shared__ float tile[64 * 65];
    int bx = blockIdx.x;
    int mat = bx >> 8;
    int tl  = bx & 255;
    int tr = tl >> 4, tc = tl & 15;
    const float* src; u16* dst;
    if      (mat <  8) { src = wg  + (size_t)mat * 1048576;        dst = wgt + (size_t)mat * 1048576; }
    else if (mat < 16) { src = wu  + (size_t)(mat - 8) * 1048576;  dst = wut + (size_t)(mat - 8) * 1048576; }
    else if (mat < 24) { src = wd  + (size_t)(mat - 16) * 1048576; dst = wdt + (size_t)(mat - 16) * 1048576; }
    else if (mat == 24){ src = wsg; dst = wsgt; }
    else if (mat == 25){ src = wsu; dst = wsut; }
    else               { src = wsd; dst = wsdt; }
    int t = threadIdx.x;
    int col = (t & 15) * 4;       // 0..60
    int r0  = t >> 4;             // 0..15
#pragma unroll
    for (int j = 0; j < 4; j++) {
        int row = r0 + j * 16;
        f32x4 v = *(const f32x4*)(src + (size_t)(tr * 64 + row) * 1024 + tc * 64 + col);
        float* tp = tile + row * 65 + col;
        tp[0] = v.x; tp[1] = v.y; tp[2] = v.z; tp[3] = v.w;
    }
    __syncthreads();
    int kc = (t & 7) * 8;         // k chunk base within tile: 0..56
#pragma unroll
    for (int it = 0; it < 2; it++) {
        int orow = (t >> 3) + it * 32;   // 0..63
        u16x8 o;
#pragma unroll
        for (int i = 0; i < 8; i++) o[i] = f2bf(tile[(kc + i) * 65 + orow]);
        *(u16x8*)(dst + (size_t)(tc * 64 + orow) * 1024 + tr * 64 + kc) = o;
    }
}

// -------- router: logits, top-2 weights, block-partial Psum/counts --------
__global__ void k_router(const float* __restrict__ x, const float* __restrict__ wgate,
                         int* __restrict__ tidx, float* __restrict__ tw,
                         float* __restrict__ Psum, int* __restrict__ cnt8) {
    __shared__ float sP[8];
    __shared__ int   sC[8];
    int t = threadIdx.x;
    if (t < 8) { sP[t] = 0.f; sC[t] = 0; }
    __syncthreads();
    int wave = t >> 6;
    int lane = t & 63;
    int n = blockIdx.x * 4 + wave;
    const float* xr = x + (size_t)n * DIM;
    float acc[8] = {0.f,0.f,0.f,0.f,0.f,0.f,0.f,0.f};
    for (int d = lane; d < DIM; d += 64) {
        float xv = xr[d];
        const float* wr = wgate + d * 8;
#pragma unroll
        for (int e = 0; e < 8; e++) acc[e] += xv * wr[e];
    }
#pragma unroll
    for (int off = 32; off; off >>= 1) {
#pragma unroll
        for (int e = 0; e < 8; e++) acc[e] += __shfl_xor(acc[e], off);
    }
    if (lane == 0) {
        float mx = acc[0];
#pragma unroll
        for (int e = 1; e < 8; e++) mx = fmaxf(mx, acc[e]);
        float p[8], s = 0.f;
#pragma unroll
        for (int e = 0; e < 8; e++) { p[e] = expf(acc[e] - mx); s += p[e]; }
        float inv = 1.f / s;
#pragma unroll
        for (int e = 0; e < 8; e++) atomicAdd(&sP[e], p[e] * inv);
        int i0 = 0; float b0 = acc[0];
#pragma unroll
        for (int e = 1; e < 8; e++) if (acc[e] > b0) { b0 = acc[e]; i0 = e; }
        int i1 = -1; float b1 = -3.4e38f;
#pragma unroll
        for (int e = 0; e < 8; e++) if (e != i0 && acc[e] > b1) { b1 = acc[e]; i1 = e; }
        float w0 = 1.f / (1.f + expf(b1 - b0));
        tidx[n * 2] = i0; tidx[n * 2 + 1] = i1;
        tw[n * 2] = w0;   tw[n * 2 + 1] = 1.f - w0;
        atomicAdd(&sC[i0], 1);
        atomicAdd(&sC[i1], 1);
    }
    __syncthreads();
    if (t < 8) {
        atomicAdd(&Psum[t], sP[t]);
        atomicAdd(&cnt8[t], sC[t]);
    }
}

// -------- scatter + fused finalize (aux loss, counts, offs) ----------
__global__ void k_scatter(const int* __restrict__ tidx, const float* __restrict__ Psum,
                          const int* __restrict__ cnt8, int* __restrict__ curs,
                          int* __restrict__ tlist, int* __restrict__ slots,
                          float* __restrict__ out, int* __restrict__ counts,
                          int* __restrict__ offs) {
    __shared__ int s_off[8];
    int t = threadIdx.x;
    if (t == 0) {
        int o = 0;
        for (int e = 0; e < 8; e++) { s_off[e] = o; o += cnt8[e]; }
    }
    __syncthreads();
    if (blockIdx.x == 0 && t == 0) {
        float aux = 0.f;
        for (int e = 0; e < 8; e++) {
            int c = cnt8[e];
            aux += (float)c * Psum[e];
            offs[e] = s_off[e]; counts[e] = c;
        }
        out[OUT_ELEMS] = 8.f * aux / ((float)N_TOK * (float)N_TOK);
        offs[8] = 4096; counts[8] = 2048;
    }
    int n = blockIdx.x * 256 + t;
    if (n < N_TOK) {
#pragma unroll
        for (int k = 0; k < 2; k++) {
            int e = tidx[n * 2 + k];
            int p = atomicAdd(&curs[e], 1);
            int sl = s_off[e] + p;
            tlist[sl] = n;
            slots[n * 2 + k] = sl;
        }
    }
}

// ---------------- GEMM1: gathered X @ [Wg|Wu], fused silu*u -> H bf16 -------
__global__ __launch_bounds__(256, 2)
void k_gemm1(const u16* __restrict__ xb, const u16* __restrict__ wgt,
             const u16* __restrict__ wut, const u16* __restrict__ wsgt,
             const u16* __restrict__ wsut, const int* __restrict__ tlist,
             const int* __restrict__ counts, const int* __restrict__ offs,
             u16* __restrict__ H) {
    int bx = blockIdx.x;
    int job = bx >> 7;
    int mt = (bx >> 3) & 15;
    int nt = bx & 7;
    int jcnt = counts[job];
    int m0 = mt << 7;
    if (m0 >= jcnt) return;
    int joff = offs[job];
    int n0 = nt << 7;
    const u16* Bg = (job < 8) ? (wgt + (size_t)job * 1048576) : wsgt;
    const u16* Bu = (job < 8) ? (wut + (size_t)job * 1048576) : wsut;

    __shared__ __attribute__((aligned(128))) u16 As[4096];
    __shared__ __attribute__((aligned(128))) u16 Bgs[4096];
    __shared__ __attribute__((aligned(128))) u16 Bus[4096];

    int t = threadIdx.x;
    int wave = t >> 6, lane = t & 63;
    int ch = (lane & 3) * 8;
    int r0 = (wave * 2 + 0) * 16 + (lane >> 2);
    int r1 = (wave * 2 + 1) * 16 + (lane >> 2);
    int tok0 = tlist[joff + m0 + r0];
    int tok1 = tlist[joff + m0 + r1];
    const u16* a0 = xb + (size_t)tok0 * 1024 + ch;
    const u16* a1 = xb + (size_t)tok1 * 1024 + ch;
    const u16* g0 = Bg + (size_t)(n0 + r0) * 1024 + ch;
    const u16* g1 = Bg + (size_t)(n0 + r1) * 1024 + ch;
    const u16* u0 = Bu + (size_t)(n0 + r0) * 1024 + ch;
    const u16* u1 = Bu + (size_t)(n0 + r1) * 1024 + ch;
    u16* lA0 = As  + (wave * 2 + 0) * 512;  u16* lA1 = As  + (wave * 2 + 1) * 512;
    u16* lG0 = Bgs + (wave * 2 + 0) * 512;  u16* lG1 = Bgs + (wave * 2 + 1) * 512;
    u16* lU0 = Bus + (wave * 2 + 0) * 512;  u16* lU1 = Bus + (wave * 2 + 1) * 512;

    int wm = (wave >> 1) << 6, wn = (wave & 1) << 6;
    int quad = lane >> 4, lr = lane & 15;

    f32x4 accg[4][4], accu[4][4];
    f32x4 zz = {0.f, 0.f, 0.f, 0.f};
#pragma unroll
    for (int i = 0; i < 4; i++)
#pragma unroll
        for (int j = 0; j < 4; j++) { accg[i][j] = zz; accu[i][j] = zz; }

    for (int k0 = 0; k0 < 1024; k0 += 32) {
        GLDS16(a0 + k0, lA0);  GLDS16(a1 + k0, lA1);
        GLDS16(g0 + k0, lG0);  GLDS16(g1 + k0, lG1);
        GLDS16(u0 + k0, lU0);  GLDS16(u1 + k0, lU1);
        __syncthreads();
        short8 af[4], bgf[4], buf[4];
#pragma unroll
        for (int i = 0; i < 4; i++) {
            af[i]  = *(const short8*)(As  + (wm + i * 16 + lr) * 32 + quad * 8);
            bgf[i] = *(const short8*)(Bgs + (wn + i * 16 + lr) * 32 + quad * 8);
            buf[i] = *(const short8*)(Bus + (wn + i * 16 + lr) * 32 + quad * 8);
        }
#pragma unroll
        for (int mi = 0; mi < 4; mi++)
#pragma unroll
            for (int ni = 0; ni < 4; ni++) {
                accg[mi][ni] = __builtin_amdgcn_mfma_f32_16x16x32_bf16(af[mi], bgf[ni], accg[mi][ni], 0, 0, 0);
                accu[mi][ni] = __builtin_amdgcn_mfma_f32_16x16x32_bf16(af[mi], buf[ni], accu[mi][ni], 0, 0, 0);
            }
        __syncthreads();
    }
#pragma unroll
    for (int mi = 0; mi < 4; mi++) {
        int rowb = m0 + wm + mi * 16 + quad * 4;
#pragma unroll
        for (int rr = 0; rr < 4; rr++) {
            int row = rowb + rr;
            if (row < jcnt) {
                size_t base = (size_t)(joff + row) * 1024 + n0 + wn;
#pragma unroll
                for (int ni = 0; ni < 4; ni++) {
                    float g = accg[mi][ni][rr];
                    float u = accu[mi][ni][rr];
                    float h = (g / (1.f + expf(-g))) * u;
                    H[base + ni * 16 + lr] = f2bf(h);
                }
            }
        }
    }
}

// ---------------- GEMM2: H @ Wd -> Y bf16 (unweighted, no atomics) ----------
__global__ __launch_bounds__(256, 2)
void k_gemm2(const u16* __restrict__ H, const u16* __restrict__ wdt,
             const u16* __restrict__ wsdt, const int* __restrict__ counts,
             const int* __restrict__ offs, u16* __restrict__ Y) {
    int bx = blockIdx.x;
    int job = bx >> 7;
    int mt = (bx >> 3) & 15;
    int nt = bx & 7;
    int jcnt = counts[job];
    int m0 = mt << 7;
    if (m0 >= jcnt) return;
    int joff = offs[job];
    int n0 = nt << 7;
    const u16* Bt = (job < 8) ? (wdt + (size_t)job * 1048576) : wsdt;

    __shared__ __attribute__((aligned(128))) u16 As[4096];
    __shared__ __attribute__((aligned(128))) u16 Bs[4096];

    int t = threadIdx.x;
    int wave = t >> 6, lane = t & 63;
    int ch = (lane & 3) * 8;
    int r0 = (wave * 2 + 0) * 16 + (lane >> 2);
    int r1 = (wave * 2 + 1) * 16 + (lane >> 2);
    const u16* a0 = H + (size_t)(joff + m0 + r0) * 1024 + ch;
    const u16* a1 = H + (size_t)(joff + m0 + r1) * 1024 + ch;
    const u16* b0 = Bt + (size_t)(n0 + r0) * 1024 + ch;
    const u16* b1 = Bt + (size_t)(n0 + r1) * 1024 + ch;
    u16* lA0 = As + (wave * 2 + 0) * 512;  u16* lA1 = As + (wave * 2 + 1) * 512;
    u16* lB0 = Bs + (wave * 2 + 0) * 512;  u16* lB1 = Bs + (wave * 2 + 1) * 512;

    int wm = (wave >> 1) << 6, wn = (wave & 1) << 6;
    int quad = lane >> 4, lr = lane & 15;

    f32x4 acc[4][4];
    f32x4 zz = {0.f, 0.f, 0.f, 0.f};
#pragma unroll
    for (int i = 0; i < 4; i++)
#pragma unroll
        for (int j = 0; j < 4; j++) acc[i][j] = zz;

    for (int k0 = 0; k0 < 1024; k0 += 32) {
        GLDS16(a0 + k0, lA0);  GLDS16(a1 + k0, lA1);
        GLDS16(b0 + k0, lB0);  GLDS16(b1 + k0, lB1);
        __syncthreads();
        short8 af[4], bf[4];
#pragma unroll
        for (int i = 0; i < 4; i++) {
            af[i] = *(const short8*)(As + (wm + i * 16 + lr) * 32 + quad * 8);
            bf[i] = *(const short8*)(Bs + (wn + i * 16 + lr) * 32 + quad * 8);
        }
#pragma unroll
        for (int mi = 0; mi < 4; mi++)
#pragma unroll
            for (int ni = 0; ni < 4; ni++)
                acc[mi][ni] = __builtin_amdgcn_mfma_f32_16x16x32_bf16(af[mi], bf[ni], acc[mi][ni], 0, 0, 0);
        __syncthreads();
    }
#pragma unroll
    for (int mi = 0; mi < 4; mi++) {
        int rowb = m0 + wm + mi * 16 + quad * 4;
#pragma unroll
        for (int rr = 0; rr < 4; rr++) {
            int row = rowb + rr;
            if (row < jcnt) {
                u16* yrow = Y + (size_t)(joff + row) * 1024 + n0 + wn;
#pragma unroll
                for (int ni = 0; ni < 4; ni++)
                    yrow[ni * 16 + lr] = f2bf(acc[mi][ni][rr]);
            }
        }
    }
}

// ---------------- combine: out[n] = w0*Y[s0] + w1*Y[s1] + Y[4096+n] ---------
__global__ void k_combine(const u16* __restrict__ Y, const int* __restrict__ slots,
                          const float* __restrict__ tw, float* __restrict__ out) {
    int n = blockIdx.x;
    int d = threadIdx.x;
    int s0 = slots[n * 2], s1 = slots[n * 2 + 1];
    float w0 = tw[n * 2], w1 = tw[n * 2 + 1];
    u16x4 y0 = ((const u16x4*)(Y + (size_t)s0 * 1024))[d];
    u16x4 y1 = ((const u16x4*)(Y + (size_t)s1 * 1024))[d];
    u16x4 ys = ((const u16x4*)(Y + (size_t)(4096 + n) * 1024))[d];
    f32x4 r;
    r.x = w0 * bf2f(y0.x) + w1 * bf2f(y1.x) + bf2f(ys.x);
    r.y = w0 * bf2f(y0.y) + w1 * bf2f(y1.y) + bf2f(ys.y);
    r.z = w0 * bf2f(y0.z) + w1 * bf2f(y1.z) + bf2f(ys.z);
    r.w = w0 * bf2f(y0.w) + w1 * bf2f(y1.w) + bf2f(ys.w);
    ((f32x4*)(out + (size_t)n * 1024))[d] = r;
}

extern "C" void kernel_launch(void* const* d_in, const int* in_sizes, int n_in,
                              void* d_out, int out_size, void* d_ws, size_t ws_size,
                              hipStream_t stream) {
    const float* x     = (const float*)d_in[0];
    const float* wgate = (const float*)d_in[1];
    const float* wg    = (const float*)d_in[2];
    const float* wu    = (const float*)d_in[3];
    const float* wd    = (const float*)d_in[4];
    const float* wsg   = (const float*)d_in[5];
    const float* wsu   = (const float*)d_in[6];
    const float* wsd   = (const float*)d_in[7];
    float* out = (float*)d_out;

    char* ws = (char*)d_ws;
    u16*   xb    = (u16*)(ws + 0);           // 4 MB
    u16*   wgt   = (u16*)(ws + 4194304);     // 16 MB
    u16*   wut   = (u16*)(ws + 20971520);    // 16 MB
    u16*   wdt   = (u16*)(ws + 37748736);    // 16 MB
    u16*   wsgt  = (u16*)(ws + 54525952);    // 2 MB
    u16*   wsut  = (u16*)(ws + 56623104);    // 2 MB
    u16*   wsdt  = (u16*)(ws + 58720256);    // 2 MB
    u16*   H     = (u16*)(ws + 60817408);    // 12 MB
    // Y (bf16) overlays wgt (dead after gemm1; gemm2 runs strictly after)
    u16*   Y     = (u16*)(ws + 4194304);     // 12.58 MB
    int*   tidx  = (int*)(ws + 73400320);
    float* tw    = (float*)(ws + 73416704);
    int*   tlist = (int*)(ws + 73433088);
    int*   slots = (int*)(ws + 73457664);
    int*   counts= (int*)(ws + 73474048);
    int*   offs  = (int*)(ws + 73474112);
    int*   curs  = (int*)(ws + 73474176);
    float* Psum  = (float*)(ws + 73474240);
    int*   cnt8  = (int*)(ws + 73474304);

    k_cvt_x<<<2048, 256, 0, stream>>>(x, xb, tlist, curs, Psum, cnt8);
    k_router<<<512, 256, 0, stream>>>(x, wgate, tidx, tw, Psum, cnt8);
    k_scatter<<<8, 256, 0, stream>>>(tidx, Psum, cnt8, curs, tlist, slots,
                                     out, counts, offs);
    k_cvt_w<<<6912, 256, 0, stream>>>(wg, wu, wd, wsg, wsu, wsd,
                                      wgt, wut, wdt, wsgt, wsut, wsdt);
    k_gemm1<<<1152, 256, 0, stream>>>(xb, wgt, wut, wsgt, wsut, tlist, counts, offs, H);
    k_gemm2<<<1152, 256, 0, stream>>>(H, wdt, wsdt, counts, offs, Y);
    k_combine<<<2048, 256, 0, stream>>>(Y, slots, tw, out);
}

// Round 5
// 279.641 us; speedup vs baseline: 1.0327x; 1.0020x over previous
//
#include <hip/hip_runtime.h>
#include <math.h>

typedef unsigned short u16;
typedef __attribute__((ext_vector_type(8))) short short8;
typedef __attribute__((ext_vector_type(4))) float f32x4;
typedef __attribute__((ext_vector_type(4))) unsigned short u16x4;
typedef __attribute__((ext_vector_type(8))) unsigned short u16x8;

#define N_TOK 2048
#define DIM 1024
#define OUT_ELEMS 2097152   // N_TOK * DIM

#define GLDS16(gp, lp) __builtin_amdgcn_global_load_lds( \
    (const __attribute__((address_space(1))) unsigned int*)(gp), \
    (__attribute__((address_space(3))) unsigned int*)(lp), 16, 0, 0)

__device__ __forceinline__ u16 f2bf(float f) {
    union { float f; unsigned u; } v; v.f = f;
    unsigned r = (v.u + 0x7FFFu + ((v.u >> 16) & 1u)) >> 16;
    return (u16)r;
}
__device__ __forceinline__ float bf2f(u16 h) {
    union { unsigned u; float f; } v; v.u = ((unsigned)h) << 16;
    return v.f;
}

// -------- init: shared token list, cursors, Psum/cnt zeros ------
__global__ void k_init(int* __restrict__ tlist, int* __restrict__ curs,
                       float* __restrict__ Psum, int* __restrict__ cnt8) {
    int i = blockIdx.x * 256 + threadIdx.x;   // 0..2047
    tlist[4096 + i] = i;
    if (i < 16) curs[i] = 0;
    if (i < 8) { Psum[i] = 0.f; cnt8[i] = 0; }
}

// ------- weights: fp32 [K,N] -> bf16 transposed [N,K], 128x128 tiles ------
// Phase 1: ALL 16 f32x4 loads issued before any LDS write (deep vmcnt queue),
// convert to bf16 in regs, ds_write_b64 into [k=128][n=136] bf16 tile.
// Phase 2: stride-136 scalar reads (2-way banks = free), u16x8 stores.
__global__ void k_cvt_w(const float* __restrict__ wg, const float* __restrict__ wu,
                        const float* __restrict__ wd, const float* __restrict__ wsg,
                        const float* __restrict__ wsu, const float* __restrict__ wsd,
                        u16* __restrict__ wgt, u16* __restrict__ wut,
                        u16* __restrict__ wdt, u16* __restrict__ wsgt,
                        u16* __restrict__ wsut, u16* __restrict__ wsdt) {
    __shared__ u16 tile[128 * 136];   // 34,816 B
    int bx = blockIdx.x;
    int mat = bx >> 6;
    int tl  = bx & 63;
    int tr = tl >> 3, tc = tl & 7;
    const float* src; u16* dst;
    if      (mat <  8) { src = wg  + (size_t)mat * 1048576;        dst = wgt + (size_t)mat * 1048576; }
    else if (mat < 16) { src = wu  + (size_t)(mat - 8) * 1048576;  dst = wut + (size_t)(mat - 8) * 1048576; }
    else if (mat < 24) { src = wd  + (size_t)(mat - 16) * 1048576; dst = wdt + (size_t)(mat - 16) * 1048576; }
    else if (mat == 24){ src = wsg; dst = wsgt; }
    else if (mat == 25){ src = wsu; dst = wsut; }
    else               { src = wsd; dst = wsdt; }
    int t = threadIdx.x;
    int col = (t & 31) * 4;       // 0..124
    int rb  = t >> 5;             // 0..7
    const float* sp = src + (size_t)(tr * 128) * 1024 + tc * 128 + col;

    f32x4 v[16];
#pragma unroll
    for (int j = 0; j < 16; j++)
        v[j] = *(const f32x4*)(sp + (size_t)(j * 8 + rb) * 1024);
#pragma unroll
    for (int j = 0; j < 16; j++) {
        int row = j * 8 + rb;
        u16x4 o;
        o.x = f2bf(v[j].x); o.y = f2bf(v[j].y); o.z = f2bf(v[j].z); o.w = f2bf(v[j].w);
        *(u16x4*)(tile + row * 136 + col) = o;
    }
    __syncthreads();
    int n  = t & 127;             // output row within tile (orig col)
    int kb = (t >> 7) * 64;       // 0 or 64
    u16* drow = dst + (size_t)(tc * 128 + n) * 1024 + tr * 128;
#pragma unroll
    for (int j = 0; j < 8; j++) {
        int kc = kb + j * 8;
        u16x8 o;
#pragma unroll
        for (int i = 0; i < 8; i++) o[i] = tile[(kc + i) * 136 + n];
        *(u16x8*)(drow + kc) = o;
    }
}

// -------- router: logits, top-2, Psum/counts, fused x->bf16 --------
__global__ void k_router(const float* __restrict__ x, const float* __restrict__ wgate,
                         u16* __restrict__ xb, int* __restrict__ tidx,
                         float* __restrict__ tw, float* __restrict__ Psum,
                         int* __restrict__ cnt8) {
    __shared__ float sP[8];
    __shared__ int   sC[8];
    int t = threadIdx.x;
    if (t < 8) { sP[t] = 0.f; sC[t] = 0; }
    __syncthreads();
    int wave = t >> 6;
    int lane = t & 63;
    int n = blockIdx.x * 4 + wave;
    const float* xr = x + (size_t)n * DIM;
    u16* xbr = xb + (size_t)n * DIM;
    float acc[8] = {0.f,0.f,0.f,0.f,0.f,0.f,0.f,0.f};
#pragma unroll
    for (int i = 0; i < 16; i++) {
        int d = lane + i * 64;
        float xv = xr[d];
        xbr[d] = f2bf(xv);
        const float* wr = wgate + d * 8;
#pragma unroll
        for (int e = 0; e < 8; e++) acc[e] += xv * wr[e];
    }
#pragma unroll
    for (int off = 32; off; off >>= 1) {
#pragma unroll
        for (int e = 0; e < 8; e++) acc[e] += __shfl_xor(acc[e], off);
    }
    if (lane == 0) {
        float mx = acc[0];
#pragma unroll
        for (int e = 1; e < 8; e++) mx = fmaxf(mx, acc[e]);
        float p[8], s = 0.f;
#pragma unroll
        for (int e = 0; e < 8; e++) { p[e] = expf(acc[e] - mx); s += p[e]; }
        float inv = 1.f / s;
#pragma unroll
        for (int e = 0; e < 8; e++) atomicAdd(&sP[e], p[e] * inv);
        int i0 = 0; float b0 = acc[0];
#pragma unroll
        for (int e = 1; e < 8; e++) if (acc[e] > b0) { b0 = acc[e]; i0 = e; }
        int i1 = -1; float b1 = -3.4e38f;
#pragma unroll
        for (int e = 0; e < 8; e++) if (e != i0 && acc[e] > b1) { b1 = acc[e]; i1 = e; }
        float w0 = 1.f / (1.f + expf(b1 - b0));
        tidx[n * 2] = i0; tidx[n * 2 + 1] = i1;
        tw[n * 2] = w0;   tw[n * 2 + 1] = 1.f - w0;
        atomicAdd(&sC[i0], 1);
        atomicAdd(&sC[i1], 1);
    }
    __syncthreads();
    if (t < 8) {
        atomicAdd(&Psum[t], sP[t]);
        atomicAdd(&cnt8[t], sC[t]);
    }
}

// -------- scatter + fused finalize (aux loss, counts, offs) ----------
__global__ void k_scatter(const int* __restrict__ tidx, const float* __restrict__ Psum,
                          const int* __restrict__ cnt8, int* __restrict__ curs,
                          int* __restrict__ tlist, int* __restrict__ slots,
                          float* __restrict__ out, int* __restrict__ counts,
                          int* __restrict__ offs) {
    __shared__ int s_off[8];
    int t = threadIdx.x;
    if (t == 0) {
        int o = 0;
        for (int e = 0; e < 8; e++) { s_off[e] = o; o += cnt8[e]; }
    }
    __syncthreads();
    if (blockIdx.x == 0 && t == 0) {
        float aux = 0.f;
        for (int e = 0; e < 8; e++) {
            int c = cnt8[e];
            aux += (float)c * Psum[e];
            offs[e] = s_off[e]; counts[e] = c;
        }
        out[OUT_ELEMS] = 8.f * aux / ((float)N_TOK * (float)N_TOK);
        offs[8] = 4096; counts[8] = 2048;
    }
    int n = blockIdx.x * 256 + t;
    if (n < N_TOK) {
#pragma unroll
        for (int k = 0; k < 2; k++) {
            int e = tidx[n * 2 + k];
            int p = atomicAdd(&curs[e], 1);
            int sl = s_off[e] + p;
            tlist[sl] = n;
            slots[n * 2 + k] = sl;
        }
    }
}

// ---------------- GEMM1: gathered X @ [Wg|Wu], fused silu*u -> H bf16 -------
__global__ __launch_bounds__(256, 2)
void k_gemm1(const u16* __restrict__ xb, const u16* __restrict__ wgt,
             const u16* __restrict__ wut, const u16* __restrict__ wsgt,
             const u16* __restrict__ wsut, const int* __restrict__ tlist,
             const int* __restrict__ counts, const int* __restrict__ offs,
             u16* __restrict__ H) {
    int bx = blockIdx.x;
    int job = bx >> 7;
    int mt = (bx >> 3) & 15;
    int nt = bx & 7;
    int jcnt = counts[job];
    int m0 = mt << 7;
    if (m0 >= jcnt) return;
    int joff = offs[job];
    int n0 = nt << 7;
    const u16* Bg = (job < 8) ? (wgt + (size_t)job * 1048576) : wsgt;
    const u16* Bu = (job < 8) ? (wut + (size_t)job * 1048576) : wsut;

    __shared__ __attribute__((aligned(128))) u16 As[4096];
    __shared__ __attribute__((aligned(128))) u16 Bgs[4096];
    __shared__ __attribute__((aligned(128))) u16 Bus[4096];

    int t = threadIdx.x;
    int wave = t >> 6, lane = t & 63;
    int ch = (lane & 3) * 8;
    int r0 = (wave * 2 + 0) * 16 + (lane >> 2);
    int r1 = (wave * 2 + 1) * 16 + (lane >> 2);
    int tok0 = tlist[joff + m0 + r0];
    int tok1 = tlist[joff + m0 + r1];
    const u16* a0 = xb + (size_t)tok0 * 1024 + ch;
    const u16* a1 = xb + (size_t)tok1 * 1024 + ch;
    const u16* g0 = Bg + (size_t)(n0 + r0) * 1024 + ch;
    const u16* g1 = Bg + (size_t)(n0 + r1) * 1024 + ch;
    const u16* u0 = Bu + (size_t)(n0 + r0) * 1024 + ch;
    const u16* u1 = Bu + (size_t)(n0 + r1) * 1024 + ch;
    u16* lA0 = As  + (wave * 2 + 0) * 512;  u16* lA1 = As  + (wave * 2 + 1) * 512;
    u16* lG0 = Bgs + (wave * 2 + 0) * 512;  u16* lG1 = Bgs + (wave * 2 + 1) * 512;
    u16* lU0 = Bus + (wave * 2 + 0) * 512;  u16* lU1 = Bus + (wave * 2 + 1) * 512;

    int wm = (wave >> 1) << 6, wn = (wave & 1) << 6;
    int quad = lane >> 4, lr = lane & 15;

    f32x4 accg[4][4], accu[4][4];
    f32x4 zz = {0.f, 0.f, 0.f, 0.f};
#pragma unroll
    for (int i = 0; i < 4; i++)
#pragma unroll
        for (int j = 0; j < 4; j++) { accg[i][j] = zz; accu[i][j] = zz; }

    for (int k0 = 0; k0 < 1024; k0 += 32) {
        GLDS16(a0 + k0, lA0);  GLDS16(a1 + k0, lA1);
        GLDS16(g0 + k0, lG0);  GLDS16(g1 + k0, lG1);
        GLDS16(u0 + k0, lU0);  GLDS16(u1 + k0, lU1);
        __syncthreads();
        short8 af[4], bgf[4], buf[4];
#pragma unroll
        for (int i = 0; i < 4; i++) {
            af[i]  = *(const short8*)(As  + (wm + i * 16 + lr) * 32 + quad * 8);
            bgf[i] = *(const short8*)(Bgs + (wn + i * 16 + lr) * 32 + quad * 8);
            buf[i] = *(const short8*)(Bus + (wn + i * 16 + lr) * 32 + quad * 8);
        }
#pragma unroll
        for (int mi = 0; mi < 4; mi++)
#pragma unroll
            for (int ni = 0; ni < 4; ni++) {
                accg[mi][ni] = __builtin_amdgcn_mfma_f32_16x16x32_bf16(af[mi], bgf[ni], accg[mi][ni], 0, 0, 0);
                accu[mi][ni] = __builtin_amdgcn_mfma_f32_16x16x32_bf16(af[mi], buf[ni], accu[mi][ni], 0, 0, 0);
            }
        __syncthreads();
    }
#pragma unroll
    for (int mi = 0; mi < 4; mi++) {
        int rowb = m0 + wm + mi * 16 + quad * 4;
#pragma unroll
        for (int rr = 0; rr < 4; rr++) {
            int row = rowb + rr;
            if (row < jcnt) {
                size_t base = (size_t)(joff + row) * 1024 + n0 + wn;
#pragma unroll
                for (int ni = 0; ni < 4; ni++) {
                    float g = accg[mi][ni][rr];
                    float u = accu[mi][ni][rr];
                    float h = (g / (1.f + expf(-g))) * u;
                    H[base + ni * 16 + lr] = f2bf(h);
                }
            }
        }
    }
}

// ---------------- GEMM2: H @ Wd -> Y bf16 (unweighted, no atomics) ----------
__global__ __launch_bounds__(256, 2)
void k_gemm2(const u16* __restrict__ H, const u16* __restrict__ wdt,
             const u16* __restrict__ wsdt, const int* __restrict__ counts,
             const int* __restrict__ offs, u16* __restrict__ Y) {
    int bx = blockIdx.x;
    int job = bx >> 7;
    int mt = (bx >> 3) & 15;
    int nt = bx & 7;
    int jcnt = counts[job];
    int m0 = mt << 7;
    if (m0 >= jcnt) return;
    int joff = offs[job];
    int n0 = nt << 7;
    const u16* Bt = (job < 8) ? (wdt + (size_t)job * 1048576) : wsdt;

    __shared__ __attribute__((aligned(128))) u16 As[4096];
    __shared__ __attribute__((aligned(128))) u16 Bs[4096];

    int t = threadIdx.x;
    int wave = t >> 6, lane = t & 63;
    int ch = (lane & 3) * 8;
    int r0 = (wave * 2 + 0) * 16 + (lane >> 2);
    int r1 = (wave * 2 + 1) * 16 + (lane >> 2);
    const u16* a0 = H + (size_t)(joff + m0 + r0) * 1024 + ch;
    const u16* a1 = H + (size_t)(joff + m0 + r1) * 1024 + ch;
    const u16* b0 = Bt + (size_t)(n0 + r0) * 1024 + ch;
    const u16* b1 = Bt + (size_t)(n0 + r1) * 1024 + ch;
    u16* lA0 = As + (wave * 2 + 0) * 512;  u16* lA1 = As + (wave * 2 + 1) * 512;
    u16* lB0 = Bs + (wave * 2 + 0) * 512;  u16* lB1 = Bs + (wave * 2 + 1) * 512;

    int wm = (wave >> 1) << 6, wn = (wave & 1) << 6;
    int quad = lane >> 4, lr = lane & 15;

    f32x4 acc[4][4];
    f32x4 zz = {0.f, 0.f, 0.f, 0.f};
#pragma unroll
    for (int i = 0; i < 4; i++)
#pragma unroll
        for (int j = 0; j < 4; j++) acc[i][j] = zz;

    for (int k0 = 0; k0 < 1024; k0 += 32) {
        GLDS16(a0 + k0, lA0);  GLDS16(a1 + k0, lA1);
        GLDS16(b0 + k0, lB0);  GLDS16(b1 + k0, lB1);
        __syncthreads();
        short8 af[4], bf[4];
#pragma unroll
        for (int i = 0; i < 4; i++) {
            af[i] = *(const short8*)(As + (wm + i * 16 + lr) * 32 + quad * 8);
            bf[i] = *(const short8*)(Bs + (wn + i * 16 + lr) * 32 + quad * 8);
        }
#pragma unroll
        for (int mi = 0; mi < 4; mi++)
#pragma unroll
            for (int ni = 0; ni < 4; ni++)
                acc[mi][ni] = __builtin_amdgcn_mfma_f32_16x16x32_bf16(af[mi], bf[ni], acc[mi][ni], 0, 0, 0);
        __syncthreads();
    }
#pragma unroll
    for (int mi = 0; mi < 4; mi++) {
        int rowb = m0 + wm + mi * 16 + quad * 4;
#pragma unroll
        for (int rr = 0; rr < 4; rr++) {
            int row = rowb + rr;
            if (row < jcnt) {
                u16* yrow = Y + (size_t)(joff + row) * 1024 + n0 + wn;
#pragma unroll
                for (int ni = 0; ni < 4; ni++)
                    yrow[ni * 16 + lr] = f2bf(acc[mi][ni][rr]);
            }
        }
    }
}

// ---------------- combine: out[n] = w0*Y[s0] + w1*Y[s1] + Y[4096+n] ---------
__global__ void k_combine(const u16* __restrict__ Y, const int* __restrict__ slots,
                          const float* __restrict__ tw, float* __restrict__ out) {
    int n = blockIdx.x;
    int d = threadIdx.x;
    int s0 = slots[n * 2], s1 = slots[n * 2 + 1];
    float w0 = tw[n * 2], w1 = tw[n * 2 + 1];
    u16x4 y0 = ((const u16x4*)(Y + (size_t)s0 * 1024))[d];
    u16x4 y1 = ((const u16x4*)(Y + (size_t)s1 * 1024))[d];
    u16x4 ys = ((const u16x4*)(Y + (size_t)(4096 + n) * 1024))[d];
    f32x4 r;
    r.x = w0 * bf2f(y0.x) + w1 * bf2f(y1.x) + bf2f(ys.x);
    r.y = w0 * bf2f(y0.y) + w1 * bf2f(y1.y) + bf2f(ys.y);
    r.z = w0 * bf2f(y0.z) + w1 * bf2f(y1.z) + bf2f(ys.z);
    r.w = w0 * bf2f(y0.w) + w1 * bf2f(y1.w) + bf2f(ys.w);
    ((f32x4*)(out + (size_t)n * 1024))[d] = r;
}

extern "C" void kernel_launch(void* const* d_in, const int* in_sizes, int n_in,
                              void* d_out, int out_size, void* d_ws, size_t ws_size,
                              hipStream_t stream) {
    const float* x     = (const float*)d_in[0];
    const float* wgate = (const float*)d_in[1];
    const float* wg    = (const float*)d_in[2];
    const float* wu    = (const float*)d_in[3];
    const float* wd    = (const float*)d_in[4];
    const float* wsg   = (const float*)d_in[5];
    const float* wsu   = (const float*)d_in[6];
    const float* wsd   = (const float*)d_in[7];
    float* out = (float*)d_out;

    char* ws = (char*)d_ws;
    u16*   xb    = (u16*)(ws + 0);           // 4 MB
    u16*   wgt   = (u16*)(ws + 4194304);     // 16 MB
    u16*   wut   = (u16*)(ws + 20971520);    // 16 MB
    u16*   wdt   = (u16*)(ws + 37748736);    // 16 MB
    u16*   wsgt  = (u16*)(ws + 54525952);    // 2 MB
    u16*   wsut  = (u16*)(ws + 56623104);    // 2 MB
    u16*   wsdt  = (u16*)(ws + 58720256);    // 2 MB
    u16*   H     = (u16*)(ws + 60817408);    // 12 MB
    // Y (bf16) overlays wgt (dead after gemm1; gemm2 runs strictly after)
    u16*   Y     = (u16*)(ws + 4194304);     // 12.58 MB
    int*   tidx  = (int*)(ws + 73400320);
    float* tw    = (float*)(ws + 73416704);
    int*   tlist = (int*)(ws + 73433088);
    int*   slots = (int*)(ws + 73457664);
    int*   counts= (int*)(ws + 73474048);
    int*   offs  = (int*)(ws + 73474112);
    int*   curs  = (int*)(ws + 73474176);
    float* Psum  = (float*)(ws + 73474240);
    int*   cnt8  = (int*)(ws + 73474304);

    k_init<<<8, 256, 0, stream>>>(tlist, curs, Psum, cnt8);
    k_router<<<512, 256, 0, stream>>>(x, wgate, xb, tidx, tw, Psum, cnt8);
    k_scatter<<<8, 256, 0, stream>>>(tidx, Psum, cnt8, curs, tlist, slots,
                                     out, counts, offs);
    k_cvt_w<<<1728, 256, 0, stream>>>(wg, wu, wd, wsg, wsu, wsd,
                                      wgt, wut, wdt, wsgt, wsut, wsdt);
    k_gemm1<<<1152, 256, 0, stream>>>(xb, wgt, wut, wsgt, wsut, tlist, counts, offs, H);
    k_gemm2<<<1152, 256, 0, stream>>>(H, wdt, wsdt, counts, offs, Y);
    k_combine<<<2048, 256, 0, stream>>>(Y, slots, tw, out);
}

// Round 6
// 271.349 us; speedup vs baseline: 1.0643x; 1.0306x over previous
//
#include <hip/hip_runtime.h>
#include <math.h>

typedef unsigned short u16;
typedef __attribute__((ext_vector_type(8))) short short8;
typedef __attribute__((ext_vector_type(4))) float f32x4;
typedef __attribute__((ext_vector_type(4))) unsigned short u16x4;
typedef __attribute__((ext_vector_type(8))) unsigned short u16x8;

#define N_TOK 2048
#define DIM 1024
#define OUT_ELEMS 2097152   // N_TOK * DIM

#define GLDS16(gp, lp) __builtin_amdgcn_global_load_lds( \
    (const __attribute__((address_space(1))) unsigned int*)(gp), \
    (__attribute__((address_space(3))) unsigned int*)(lp), 16, 0, 0)

__device__ __forceinline__ u16 f2bf(float f) {
    union { float f; unsigned u; } v; v.f = f;
    unsigned r = (v.u + 0x7FFFu + ((v.u >> 16) & 1u)) >> 16;
    return (u16)r;
}
__device__ __forceinline__ float bf2f(u16 h) {
    union { unsigned u; float f; } v; v.u = ((unsigned)h) << 16;
    return v.f;
}

// -------- init: shared token list, cursors, Psum/cnt zeros ------
__global__ void k_init(int* __restrict__ tlist, int* __restrict__ curs,
                       float* __restrict__ Psum, int* __restrict__ cnt8) {
    int i = blockIdx.x * 256 + threadIdx.x;   // 0..2047
    tlist[4096 + i] = i;
    if (i < 16) curs[i] = 0;
    if (i < 8) { Psum[i] = 0.f; cnt8[i] = 0; }
}

// ------- weights: fp32 [K,N] -> bf16 CHUNK-TRANSPOSED W'[k/8][n][8] -------
// One block = 8 full source rows (8x4KB contiguous reads) -> 16KB LDS ->
// one 16KB fully-contiguous write. No fragmented DRAM access anywhere.
__global__ void k_cvt_w(const float* __restrict__ wg, const float* __restrict__ wu,
                        const float* __restrict__ wd, const float* __restrict__ wsg,
                        const float* __restrict__ wsu, const float* __restrict__ wsd,
                        u16* __restrict__ wgt, u16* __restrict__ wut,
                        u16* __restrict__ wdt, u16* __restrict__ wsgt,
                        u16* __restrict__ wsut, u16* __restrict__ wsdt) {
    __shared__ u16 tile[8 * 1024];   // 16 KB
    int bx = blockIdx.x;             // 27 * 128
    int mat = bx >> 7;
    int chunk = bx & 127;            // k-chunk (8 rows)
    const float* src; u16* dst;
    if      (mat <  8) { src = wg  + (size_t)mat * 1048576;        dst = wgt + (size_t)mat * 1048576; }
    else if (mat < 16) { src = wu  + (size_t)(mat - 8) * 1048576;  dst = wut + (size_t)(mat - 8) * 1048576; }
    else if (mat < 24) { src = wd  + (size_t)(mat - 16) * 1048576; dst = wdt + (size_t)(mat - 16) * 1048576; }
    else if (mat == 24){ src = wsg; dst = wsgt; }
    else if (mat == 25){ src = wsu; dst = wsut; }
    else               { src = wsd; dst = wsdt; }
    const float* srow = src + (size_t)chunk * 8192;   // 8 rows of 1024
    u16* dchunk = dst + (size_t)chunk * 8192;         // 16KB contiguous out
    int t = threadIdx.x;
    int r  = t >> 5;                 // 0..7
    int c0 = (t & 31) * 4;           // 0..124
    f32x4 v[8];
#pragma unroll
    for (int j = 0; j < 8; j++)
        v[j] = *(const f32x4*)(srow + r * 1024 + c0 + j * 128);
#pragma unroll
    for (int j = 0; j < 8; j++) {
        u16x4 o;
        o.x = f2bf(v[j].x); o.y = f2bf(v[j].y); o.z = f2bf(v[j].z); o.w = f2bf(v[j].w);
        *(u16x4*)(tile + r * 1024 + c0 + j * 128) = o;
    }
    __syncthreads();
#pragma unroll
    for (int j = 0; j < 4; j++) {
        int n = t + j * 256;
        u16x8 o;
#pragma unroll
        for (int k = 0; k < 8; k++) o[k] = tile[k * 1024 + n];
        *(u16x8*)(dchunk + n * 8) = o;
    }
}

// -------- router: logits, top-2, Psum/counts, fused x->bf16 --------
__global__ void k_router(const float* __restrict__ x, const float* __restrict__ wgate,
                         u16* __restrict__ xb, int* __restrict__ tidx,
                         float* __restrict__ tw, float* __restrict__ Psum,
                         int* __restrict__ cnt8) {
    __shared__ float sP[8];
    __shared__ int   sC[8];
    int t = threadIdx.x;
    if (t < 8) { sP[t] = 0.f; sC[t] = 0; }
    __syncthreads();
    int wave = t >> 6;
    int lane = t & 63;
    int n = blockIdx.x * 4 + wave;
    const float* xr = x + (size_t)n * DIM;
    u16* xbr = xb + (size_t)n * DIM;
    float acc[8] = {0.f,0.f,0.f,0.f,0.f,0.f,0.f,0.f};
#pragma unroll
    for (int i = 0; i < 16; i++) {
        int d = lane + i * 64;
        float xv = xr[d];
        xbr[d] = f2bf(xv);
        const float* wr = wgate + d * 8;
#pragma unroll
        for (int e = 0; e < 8; e++) acc[e] += xv * wr[e];
    }
#pragma unroll
    for (int off = 32; off; off >>= 1) {
#pragma unroll
        for (int e = 0; e < 8; e++) acc[e] += __shfl_xor(acc[e], off);
    }
    if (lane == 0) {
        float mx = acc[0];
#pragma unroll
        for (int e = 1; e < 8; e++) mx = fmaxf(mx, acc[e]);
        float p[8], s = 0.f;
#pragma unroll
        for (int e = 0; e < 8; e++) { p[e] = expf(acc[e] - mx); s += p[e]; }
        float inv = 1.f / s;
#pragma unroll
        for (int e = 0; e < 8; e++) atomicAdd(&sP[e], p[e] * inv);
        int i0 = 0; float b0 = acc[0];
#pragma unroll
        for (int e = 1; e < 8; e++) if (acc[e] > b0) { b0 = acc[e]; i0 = e; }
        int i1 = -1; float b1 = -3.4e38f;
#pragma unroll
        for (int e = 0; e < 8; e++) if (e != i0 && acc[e] > b1) { b1 = acc[e]; i1 = e; }
        float w0 = 1.f / (1.f + expf(b1 - b0));
        tidx[n * 2] = i0; tidx[n * 2 + 1] = i1;
        tw[n * 2] = w0;   tw[n * 2 + 1] = 1.f - w0;
        atomicAdd(&sC[i0], 1);
        atomicAdd(&sC[i1], 1);
    }
    __syncthreads();
    if (t < 8) {
        atomicAdd(&Psum[t], sP[t]);
        atomicAdd(&cnt8[t], sC[t]);
    }
}

// -------- scatter + fused finalize (aux loss, counts, offs) ----------
__global__ void k_scatter(const int* __restrict__ tidx, const float* __restrict__ Psum,
                          const int* __restrict__ cnt8, int* __restrict__ curs,
                          int* __restrict__ tlist, int* __restrict__ slots,
                          float* __restrict__ out, int* __restrict__ counts,
                          int* __restrict__ offs) {
    __shared__ int s_off[8];
    int t = threadIdx.x;
    if (t == 0) {
        int o = 0;
        for (int e = 0; e < 8; e++) { s_off[e] = o; o += cnt8[e]; }
    }
    __syncthreads();
    if (blockIdx.x == 0 && t == 0) {
        float aux = 0.f;
        for (int e = 0; e < 8; e++) {
            int c = cnt8[e];
            aux += (float)c * Psum[e];
            offs[e] = s_off[e]; counts[e] = c;
        }
        out[OUT_ELEMS] = 8.f * aux / ((float)N_TOK * (float)N_TOK);
        offs[8] = 4096; counts[8] = 2048;
    }
    int n = blockIdx.x * 256 + t;
    if (n < N_TOK) {
#pragma unroll
        for (int k = 0; k < 2; k++) {
            int e = tidx[n * 2 + k];
            int p = atomicAdd(&curs[e], 1);
            int sl = s_off[e] + p;
            tlist[sl] = n;
            slots[n * 2 + k] = sl;
        }
    }
}

// ---------------- GEMM1: gathered X @ [Wg|Wu], fused silu*u -> H bf16 -------
// B in chunked layout W'[k/8][n][8]; per-k0 slabs are 2KB contiguous.
__global__ __launch_bounds__(256, 2)
void k_gemm1(const u16* __restrict__ xb, const u16* __restrict__ wgt,
             const u16* __restrict__ wut, const u16* __restrict__ wsgt,
             const u16* __restrict__ wsut, const int* __restrict__ tlist,
             const int* __restrict__ counts, const int* __restrict__ offs,
             u16* __restrict__ H) {
    int bx = blockIdx.x;
    int job = bx >> 7;
    int mt = (bx >> 3) & 15;
    int nt = bx & 7;
    int jcnt = counts[job];
    int m0 = mt << 7;
    if (m0 >= jcnt) return;
    int joff = offs[job];
    int n0 = nt << 7;
    const u16* Bg = (job < 8) ? (wgt + (size_t)job * 1048576) : wsgt;
    const u16* Bu = (job < 8) ? (wut + (size_t)job * 1048576) : wsut;

    __shared__ __attribute__((aligned(128))) u16 As[4096];
    __shared__ __attribute__((aligned(128))) u16 Bgs[4096];
    __shared__ __attribute__((aligned(128))) u16 Bus[4096];

    int t = threadIdx.x;
    int wave = t >> 6, lane = t & 63;
    int ch = (lane & 3) * 8;
    int r0 = (wave * 2 + 0) * 16 + (lane >> 2);
    int r1 = (wave * 2 + 1) * 16 + (lane >> 2);
    int tok0 = tlist[joff + m0 + r0];
    int tok1 = tlist[joff + m0 + r1];
    const u16* a0 = xb + (size_t)tok0 * 1024 + ch;
    const u16* a1 = xb + (size_t)tok1 * 1024 + ch;
    // B slabs: wave w stages k-chunk q=w; halves n0+lane, n0+64+lane
    const u16* gB = Bg + (size_t)wave * 8192 + (size_t)(n0 + lane) * 8;
    const u16* uB = Bu + (size_t)wave * 8192 + (size_t)(n0 + lane) * 8;
    u16* lA0 = As  + (wave * 2 + 0) * 512;  u16* lA1 = As  + (wave * 2 + 1) * 512;
    u16* lGa = Bgs + wave * 1024;           u16* lGb = Bgs + wave * 1024 + 512;
    u16* lUa = Bus + wave * 1024;           u16* lUb = Bus + wave * 1024 + 512;

    int wm = (wave >> 1) << 6, wn = (wave & 1) << 6;
    int quad = lane >> 4, lr = lane & 15;

    f32x4 accg[4][4], accu[4][4];
    f32x4 zz = {0.f, 0.f, 0.f, 0.f};
#pragma unroll
    for (int i = 0; i < 4; i++)
#pragma unroll
        for (int j = 0; j < 4; j++) { accg[i][j] = zz; accu[i][j] = zz; }

    for (int k0 = 0; k0 < 1024; k0 += 32) {
        size_t koff = (size_t)k0 * 1024;   // k0/8 chunks * 8192
        GLDS16(a0 + k0, lA0);        GLDS16(a1 + k0, lA1);
        GLDS16(gB + koff, lGa);      GLDS16(gB + koff + 512, lGb);
        GLDS16(uB + koff, lUa);      GLDS16(uB + koff + 512, lUb);
        __syncthreads();
        short8 af[4], bgf[4], buf[4];
#pragma unroll
        for (int i = 0; i < 4; i++) {
            int nrow = wn + i * 16 + lr;
            af[i]  = *(const short8*)(As  + (wm + i * 16 + lr) * 32 + quad * 8);
            bgf[i] = *(const short8*)(Bgs + quad * 1024 + nrow * 8);
            buf[i] = *(const short8*)(Bus + quad * 1024 + nrow * 8);
        }
#pragma unroll
        for (int mi = 0; mi < 4; mi++)
#pragma unroll
            for (int ni = 0; ni < 4; ni++) {
                accg[mi][ni] = __builtin_amdgcn_mfma_f32_16x16x32_bf16(af[mi], bgf[ni], accg[mi][ni], 0, 0, 0);
                accu[mi][ni] = __builtin_amdgcn_mfma_f32_16x16x32_bf16(af[mi], buf[ni], accu[mi][ni], 0, 0, 0);
            }
        __syncthreads();
    }
#pragma unroll
    for (int mi = 0; mi < 4; mi++) {
        int rowb = m0 + wm + mi * 16 + quad * 4;
#pragma unroll
        for (int rr = 0; rr < 4; rr++) {
            int row = rowb + rr;
            if (row < jcnt) {
                size_t base = (size_t)(joff + row) * 1024 + n0 + wn;
#pragma unroll
                for (int ni = 0; ni < 4; ni++) {
                    float g = accg[mi][ni][rr];
                    float u = accu[mi][ni][rr];
                    float h = (g / (1.f + expf(-g))) * u;
                    H[base + ni * 16 + lr] = f2bf(h);
                }
            }
        }
    }
}

// ---------------- GEMM2: H @ Wd -> Y bf16 (unweighted, no atomics) ----------
__global__ __launch_bounds__(256, 2)
void k_gemm2(const u16* __restrict__ H, const u16* __restrict__ wdt,
             const u16* __restrict__ wsdt, const int* __restrict__ counts,
             const int* __restrict__ offs, u16* __restrict__ Y) {
    int bx = blockIdx.x;
    int job = bx >> 7;
    int mt = (bx >> 3) & 15;
    int nt = bx & 7;
    int jcnt = counts[job];
    int m0 = mt << 7;
    if (m0 >= jcnt) return;
    int joff = offs[job];
    int n0 = nt << 7;
    const u16* Bt = (job < 8) ? (wdt + (size_t)job * 1048576) : wsdt;

    __shared__ __attribute__((aligned(128))) u16 As[4096];
    __shared__ __attribute__((aligned(128))) u16 Bs[4096];

    int t = threadIdx.x;
    int wave = t >> 6, lane = t & 63;
    int ch = (lane & 3) * 8;
    int r0 = (wave * 2 + 0) * 16 + (lane >> 2);
    int r1 = (wave * 2 + 1) * 16 + (lane >> 2);
    const u16* a0 = H + (size_t)(joff + m0 + r0) * 1024 + ch;
    const u16* a1 = H + (size_t)(joff + m0 + r1) * 1024 + ch;
    const u16* bB = Bt + (size_t)wave * 8192 + (size_t)(n0 + lane) * 8;
    u16* lA0 = As + (wave * 2 + 0) * 512;  u16* lA1 = As + (wave * 2 + 1) * 512;
    u16* lBa = Bs + wave * 1024;           u16* lBb = Bs + wave * 1024 + 512;

    int wm = (wave >> 1) << 6, wn = (wave & 1) << 6;
    int quad = lane >> 4, lr = lane & 15;

    f32x4 acc[4][4];
    f32x4 zz = {0.f, 0.f, 0.f, 0.f};
#pragma unroll
    for (int i = 0; i < 4; i++)
#pragma unroll
        for (int j = 0; j < 4; j++) acc[i][j] = zz;

    for (int k0 = 0; k0 < 1024; k0 += 32) {
        size_t koff = (size_t)k0 * 1024;
        GLDS16(a0 + k0, lA0);    GLDS16(a1 + k0, lA1);
        GLDS16(bB + koff, lBa);  GLDS16(bB + koff + 512, lBb);
        __syncthreads();
        short8 af[4], bf[4];
#pragma unroll
        for (int i = 0; i < 4; i++) {
            af[i] = *(const short8*)(As + (wm + i * 16 + lr) * 32 + quad * 8);
            bf[i] = *(const short8*)(Bs + quad * 1024 + (wn + i * 16 + lr) * 8);
        }
#pragma unroll
        for (int mi = 0; mi < 4; mi++)
#pragma unroll
            for (int ni = 0; ni < 4; ni++)
                acc[mi][ni] = __builtin_amdgcn_mfma_f32_16x16x32_bf16(af[mi], bf[ni], acc[mi][ni], 0, 0, 0);
        __syncthreads();
    }
#pragma unroll
    for (int mi = 0; mi < 4; mi++) {
        int rowb = m0 + wm + mi * 16 + quad * 4;
#pragma unroll
        for (int rr = 0; rr < 4; rr++) {
            int row = rowb + rr;
            if (row < jcnt) {
                u16* yrow = Y + (size_t)(joff + row) * 1024 + n0 + wn;
#pragma unroll
                for (int ni = 0; ni < 4; ni++)
                    yrow[ni * 16 + lr] = f2bf(acc[mi][ni][rr]);
            }
        }
    }
}

// ---------------- combine: out[n] = w0*Y[s0] + w1*Y[s1] + Y[4096+n] ---------
__global__ void k_combine(const u16* __restrict__ Y, const int* __restrict__ slots,
                          const float* __restrict__ tw, float* __restrict__ out) {
    int n = blockIdx.x;
    int d = threadIdx.x;
    int s0 = slots[n * 2], s1 = slots[n * 2 + 1];
    float w0 = tw[n * 2], w1 = tw[n * 2 + 1];
    u16x4 y0 = ((const u16x4*)(Y + (size_t)s0 * 1024))[d];
    u16x4 y1 = ((const u16x4*)(Y + (size_t)s1 * 1024))[d];
    u16x4 ys = ((const u16x4*)(Y + (size_t)(4096 + n) * 1024))[d];
    f32x4 r;
    r.x = w0 * bf2f(y0.x) + w1 * bf2f(y1.x) + bf2f(ys.x);
    r.y = w0 * bf2f(y0.y) + w1 * bf2f(y1.y) + bf2f(ys.y);
    r.z = w0 * bf2f(y0.z) + w1 * bf2f(y1.z) + bf2f(ys.z);
    r.w = w0 * bf2f(y0.w) + w1 * bf2f(y1.w) + bf2f(ys.w);
    ((f32x4*)(out + (size_t)n * 1024))[d] = r;
}

extern "C" void kernel_launch(void* const* d_in, const int* in_sizes, int n_in,
                              void* d_out, int out_size, void* d_ws, size_t ws_size,
                              hipStream_t stream) {
    const float* x     = (const float*)d_in[0];
    const float* wgate = (const float*)d_in[1];
    const float* wg    = (const float*)d_in[2];
    const float* wu    = (const float*)d_in[3];
    const float* wd    = (const float*)d_in[4];
    const float* wsg   = (const float*)d_in[5];
    const float* wsu   = (const float*)d_in[6];
    const float* wsd   = (const float*)d_in[7];
    float* out = (float*)d_out;

    char* ws = (char*)d_ws;
    u16*   xb    = (u16*)(ws + 0);           // 4 MB
    u16*   wgt   = (u16*)(ws + 4194304);     // 16 MB
    u16*   wut   = (u16*)(ws + 20971520);    // 16 MB
    u16*   wdt   = (u16*)(ws + 37748736);    // 16 MB
    u16*   wsgt  = (u16*)(ws + 54525952);    // 2 MB
    u16*   wsut  = (u16*)(ws + 56623104);    // 2 MB
    u16*   wsdt  = (u16*)(ws + 58720256);    // 2 MB
    u16*   H     = (u16*)(ws + 60817408);    // 12 MB
    // Y (bf16) overlays wgt (dead after gemm1; gemm2 runs strictly after)
    u16*   Y     = (u16*)(ws + 4194304);     // 12.58 MB
    int*   tidx  = (int*)(ws + 73400320);
    float* tw    = (float*)(ws + 73416704);
    int*   tlist = (int*)(ws + 73433088);
    int*   slots = (int*)(ws + 73457664);
    int*   counts= (int*)(ws + 73474048);
    int*   offs  = (int*)(ws + 73474112);
    int*   curs  = (int*)(ws + 73474176);
    float* Psum  = (float*)(ws + 73474240);
    int*   cnt8  = (int*)(ws + 73474304);

    k_init<<<8, 256, 0, stream>>>(tlist, curs, Psum, cnt8);
    k_router<<<512, 256, 0, stream>>>(x, wgate, xb, tidx, tw, Psum, cnt8);
    k_scatter<<<8, 256, 0, stream>>>(tidx, Psum, cnt8, curs, tlist, slots,
                                     out, counts, offs);
    k_cvt_w<<<3456, 256, 0, stream>>>(wg, wu, wd, wsg, wsu, wsd,
                                      wgt, wut, wdt, wsgt, wsut, wsdt);
    k_gemm1<<<1152, 256, 0, stream>>>(xb, wgt, wut, wsgt, wsut, tlist, counts, offs, H);
    k_gemm2<<<1152, 256, 0, stream>>>(H, wdt, wsdt, counts, offs, Y);
    k_combine<<<2048, 256, 0, stream>>>(Y, slots, tw, out);
}